// Round 4
// baseline (21.682 us; speedup 1.0000x reference)
//
#include <hip/hip_runtime.h>
#include <hip/hip_bf16.h>

#define CE_T_DEV 5
#define EPS_DEV 1e-6f
#define BLK 512           // 8 waves = 8 rows per block

typedef float f32x4 __attribute__((ext_vector_type(4)));  // clang vector: nontemporal-ok

// butterfly: every lane ends with the full 64-lane sum
__device__ __forceinline__ float wave_bcast_sum(float v) {
#pragma unroll
  for (int m = 1; m < 64; m <<= 1) v += __shfl_xor(v, m, 64);
  return v;
}

// One WAVE per row, one pass over K classes, 5 scalar accumulators:
//   lg  = sum_i log(1+e^{d_i})  (= -ignorance_log)
//   sed = sum_i e^{d_i}
//   sq2 = sum_i e^{2 d_i}
//   c_ed = e^{d}@label,  c_d = d@label
// Closed forms (Se = S*exp(ign)):
//   S_a = Se*sed + K ; sum(alpha^2) = Se^2*sq2 + 2*Se*sed + K
//   err = sa2/S_a^2 - 2*alpha_lab/S_a + 1
//   var = (S_a^2 - sa2)/(S_a^2 (S_a+1))
//   sum_i ce_i = lg - c_d ;  belief_gt = c_ed/(1+c_ed) ; pmax = 1-exp(ign)
__global__ __launch_bounds__(BLK) void loss_kernel(
    const float* __restrict__ logits,
    const int* __restrict__ labels,
    const int* __restrict__ epoch_p,
    float* __restrict__ out,
    int B, int K) {
  const int tid = threadIdx.x;
  const int lane = tid & 63;
  const int wv = tid >> 6;
  constexpr int NW = BLK / 64;
  __shared__ float sm[NW];
  const int row = blockIdx.x * NW + wv;

  float contrib = 0.f;
  if (row < B) {
    const int label = labels[row];
    const float* __restrict__ rp = logits + (size_t)row * (size_t)(2 * K);
    const int pairs = K >> 1;
    const int nf = pairs >> 6;        // full 64-wide iterations
    const int rem = pairs & 63;

    float lg = 0.f, sed = 0.f, sq2 = 0.f, c_ed = 0.f, c_d = 0.f;

#define BODY(L0, L1, IDX)                                   \
    {                                                       \
      const float d = (L0) - (L1);                          \
      const float ed = __expf(d);                           \
      lg += __logf(1.f + ed);                               \
      sed += ed;                                            \
      sq2 = fmaf(ed, ed, sq2);                              \
      const bool is = ((IDX) == label);                     \
      c_ed = is ? ed : c_ed;                                \
      c_d = is ? d : c_d;                                   \
    }

    for (int i = 0; i < nf; ++i) {
      const int p = (i << 6) + lane;
      const f32x4 v = __builtin_nontemporal_load(
          reinterpret_cast<const f32x4*>(rp + 4 * (size_t)p));
      BODY(v.x, v.y, 2 * p)
      BODY(v.z, v.w, 2 * p + 1)
    }
    if (lane < rem) {
      const int p = (nf << 6) + lane;
      const f32x4 v = __builtin_nontemporal_load(
          reinterpret_cast<const f32x4*>(rp + 4 * (size_t)p));
      BODY(v.x, v.y, 2 * p)
      BODY(v.z, v.w, 2 * p + 1)
    }
    if ((K & 1) && lane == 0) {       // odd-K tail (unused for K=1000)
      const float l0 = rp[2 * (size_t)(K - 1)];
      const float l1 = rp[2 * (size_t)(K - 1) + 1];
      BODY(l0, l1, K - 1)
    }
#undef BODY

    lg   = wave_bcast_sum(lg);
    sed  = wave_bcast_sum(sed);
    sq2  = wave_bcast_sum(sq2);
    c_ed = wave_bcast_sum(c_ed);   // only owning lane nonzero -> sum == value
    c_d  = wave_bcast_sum(c_d);

    const float ign = -lg;
    const float eign = __expf(ign);
    const float S = (float)K / ((1.f - eign * sed) + EPS_DEV);
    const float Se = S * eign;
    const float S_a = Se * sed + (float)K;
    const float inv_Sa = 1.f / S_a;
    const float sa2 = Se * Se * sq2 + 2.f * Se * sed + (float)K;
    const float alpha_lab = Se * c_ed + 1.f;
    const float err = sa2 * inv_Sa * inv_Sa - 2.f * alpha_lab * inv_Sa + 1.f;
    const float var = (S_a * S_a - sa2) / (S_a * S_a * (S_a + 1.f));
    const float bgt = c_ed / (1.f + c_ed);          // plausibility @ label
    const float pmax = 1.f - eign;
    const float edl2 = (bgt - pmax) * (bgt - pmax);
    contrib = (err + var + edl2) / (float)B;
    if (epoch_p[0] < CE_T_DEV) contrib += (lg - c_d) / ((float)B * (float)K);
  }

  if (lane == 0) sm[wv] = contrib;
  __syncthreads();
  if (tid == 0) {
    float s = 0.f;
#pragma unroll
    for (int w = 0; w < NW; ++w) s += sm[w];
    atomicAdd(out, s);
  }
}

extern "C" void kernel_launch(void* const* d_in, const int* in_sizes, int n_in,
                              void* d_out, int out_size, void* d_ws, size_t ws_size,
                              hipStream_t stream) {
  const float* logits = (const float*)d_in[0];
  const int* labels = (const int*)d_in[1];
  const int* epoch = (const int*)d_in[2];
  float* out = (float*)d_out;

  const int B = in_sizes[1];
  const int K = in_sizes[0] / (2 * B);
  constexpr int ROWS_PER_BLK = BLK / 64;
  const int grid = (B + ROWS_PER_BLK - 1) / ROWS_PER_BLK;

  (void)hipMemsetAsync(d_out, 0, sizeof(float), stream);
  loss_kernel<<<grid, BLK, 0, stream>>>(logits, labels, epoch, out, B, K);
}

// Round 5
// 16.544 us; speedup vs baseline: 1.3106x; 1.3106x over previous
//
#include <hip/hip_runtime.h>
#include <hip/hip_bf16.h>

#define CE_T_DEV 5
#define EPS_DEV 1e-6f
#define BLK 256           // 4 waves = 4 rows per block

// butterfly: every lane ends with the full 64-lane sum
__device__ __forceinline__ float wave_bcast_sum(float v) {
#pragma unroll
  for (int m = 1; m < 64; m <<= 1) v += __shfl_xor(v, m, 64);
  return v;
}

__global__ void zero_kernel(float* out) { out[0] = 0.0f; }

// One WAVE per row, one pass over K classes, 5 scalar accumulators:
//   lg  = sum_i log(1+e^{d_i})  (= -ignorance_log)
//   sed = sum_i e^{d_i} ;  sq2 = sum_i e^{2 d_i}
//   c_ed = e^{d}@label ;  c_d = d@label
// Closed forms (Se = S*exp(ign)):
//   S_a = Se*sed + K ; sum(alpha^2) = Se^2*sq2 + 2*Se*sed + K
//   err = sa2/S_a^2 - 2*alpha_lab/S_a + 1
//   var = (S_a^2 - sa2)/(S_a^2 (S_a+1))
//   sum_i ce_i = lg - c_d ; belief_gt = c_ed/(1+c_ed) ; pmax = 1-exp(ign)
template <bool USE_WS>
__global__ __launch_bounds__(BLK) void loss_kernel(
    const float* __restrict__ logits,
    const int* __restrict__ labels,
    const int* __restrict__ epoch_p,
    float* __restrict__ row_out,   // USE_WS: ws[B]; else out[0] via atomic
    int B, int K) {
  const int tid = threadIdx.x;
  const int lane = tid & 63;
  const int wv = tid >> 6;
  constexpr int NW = BLK / 64;
  const int row = blockIdx.x * NW + wv;
  if (row >= B) return;

  const int label = labels[row];
  const float* __restrict__ rp = logits + (size_t)row * (size_t)(2 * K);
  const int pairs = K >> 1;
  const int nf = pairs >> 6;        // full 64-wide iterations
  const int rem = pairs & 63;

  float lg = 0.f, sed = 0.f, sq2 = 0.f, c_ed = 0.f, c_d = 0.f;

#define BODY(L0, L1, IDX)                                   \
  {                                                         \
    const float d = (L0) - (L1);                            \
    const float ed = __expf(d);                             \
    lg += __logf(1.f + ed);                                 \
    sed += ed;                                              \
    sq2 = fmaf(ed, ed, sq2);                                \
    const bool is = ((IDX) == label);                       \
    c_ed = is ? ed : c_ed;                                  \
    c_d = is ? d : c_d;                                     \
  }

#pragma unroll 2
  for (int i = 0; i < nf; ++i) {
    const int p = (i << 6) + lane;
    const float4 v = *reinterpret_cast<const float4*>(rp + 4 * (size_t)p);
    BODY(v.x, v.y, 2 * p)
    BODY(v.z, v.w, 2 * p + 1)
  }
  if (lane < rem) {
    const int p = (nf << 6) + lane;
    const float4 v = *reinterpret_cast<const float4*>(rp + 4 * (size_t)p);
    BODY(v.x, v.y, 2 * p)
    BODY(v.z, v.w, 2 * p + 1)
  }
  if ((K & 1) && lane == 0) {       // odd-K tail (unused for K=1000)
    const float l0 = rp[2 * (size_t)(K - 1)];
    const float l1 = rp[2 * (size_t)(K - 1) + 1];
    BODY(l0, l1, K - 1)
  }
#undef BODY

  lg   = wave_bcast_sum(lg);
  sed  = wave_bcast_sum(sed);
  sq2  = wave_bcast_sum(sq2);
  c_ed = wave_bcast_sum(c_ed);   // only owning lane nonzero -> sum == value
  c_d  = wave_bcast_sum(c_d);

  if (lane == 0) {
    const float ign = -lg;
    const float eign = __expf(ign);
    const float S = (float)K / ((1.f - eign * sed) + EPS_DEV);
    const float Se = S * eign;
    const float S_a = Se * sed + (float)K;
    const float inv_Sa = 1.f / S_a;
    const float sa2 = Se * Se * sq2 + 2.f * Se * sed + (float)K;
    const float alpha_lab = Se * c_ed + 1.f;
    const float err = sa2 * inv_Sa * inv_Sa - 2.f * alpha_lab * inv_Sa + 1.f;
    const float var = (S_a * S_a - sa2) / (S_a * S_a * (S_a + 1.f));
    const float bgt = c_ed / (1.f + c_ed);          // plausibility @ label
    const float pmax = 1.f - eign;
    const float edl2 = (bgt - pmax) * (bgt - pmax);
    float contrib = (err + var + edl2) / (float)B;
    if (epoch_p[0] < CE_T_DEV) contrib += (lg - c_d) / ((float)B * (float)K);
    if (USE_WS) row_out[row] = contrib;
    else        atomicAdd(row_out, contrib);
  }
}

__global__ __launch_bounds__(256) void reduce_kernel(const float* __restrict__ ws,
                                                     float* __restrict__ out, int B) {
  const int tid = threadIdx.x;
  const int lane = tid & 63;
  const int wv = tid >> 6;
  __shared__ float sm[4];
  float acc = 0.f;
  for (int i = tid; i < B; i += 256) acc += ws[i];
  acc = wave_bcast_sum(acc);
  if (lane == 0) sm[wv] = acc;
  __syncthreads();
  if (tid == 0) out[0] = sm[0] + sm[1] + sm[2] + sm[3];
}

extern "C" void kernel_launch(void* const* d_in, const int* in_sizes, int n_in,
                              void* d_out, int out_size, void* d_ws, size_t ws_size,
                              hipStream_t stream) {
  const float* logits = (const float*)d_in[0];
  const int* labels = (const int*)d_in[1];
  const int* epoch = (const int*)d_in[2];
  float* out = (float*)d_out;

  const int B = in_sizes[1];
  const int K = in_sizes[0] / (2 * B);
  constexpr int ROWS_PER_BLK = BLK / 64;
  const int grid = (B + ROWS_PER_BLK - 1) / ROWS_PER_BLK;

  if (ws_size >= (size_t)B * sizeof(float)) {
    float* ws = (float*)d_ws;
    loss_kernel<true><<<grid, BLK, 0, stream>>>(logits, labels, epoch, ws, B, K);
    reduce_kernel<<<1, 256, 0, stream>>>(ws, out, B);
  } else {
    zero_kernel<<<1, 64, 0, stream>>>(out);
    loss_kernel<false><<<grid, BLK, 0, stream>>>(logits, labels, epoch, out, B, K);
  }
}